// Round 4
// baseline (318.939 us; speedup 1.0000x reference)
//
#include <hip/hip_runtime.h>

// v: [E, 64, 3] f32, k: [E, 8, 16] f32, q: [N, 8, 16] f32, dst: [E] i32
// out: [N, 64, 3] f32.  H=8 heads, T=16, 8 value channels/head, D=3.
#define HH 8
#define CAPL 128     // per-wave LDS exp cache (Poisson(16): P(deg>128) ~ 1e-58)
#define BSTRIDE 256  // bucket capacity = max supported degree

static constexpr float SCALE = 0.08838834764831843f;  // 1/sqrt(8*16)

struct f3 {
  float x, y, z;
};  // stride-12 loads -> global_load_dwordx3

typedef float vf4 __attribute__((ext_vector_type(4)));

// Pass A: edge-major. Stream k coalesced (nontemporal: zero reuse), gather q
// (25.6 MB, L3-resident, ~16x reuse), compute logits, bucket-append edge:
// eid[dst][pos] = e and lgS[dst][pos][h] = logit (bucket-major so the node
// pass reads logits contiguously). 8 lanes per edge, one atomic per edge.
__global__ __launch_bounds__(256) void edge_kernel(
    const float* __restrict__ k, const float* __restrict__ q,
    const int* __restrict__ dst, int* __restrict__ cursor,
    int* __restrict__ eid, float* __restrict__ lgS, int E) {
  int t = blockIdx.x * 256 + threadIdx.x;
  int e = t >> 3;
  if (e >= E) return;
  int h = t & 7;
  int lane = threadIdx.x & 63;
  int d = dst[e];  // 8-lane broadcast per edge

  const vf4* kk = (const vf4*)(k + (size_t)e * 128 + h * 16);
  const vf4* qq = (const vf4*)(q + (size_t)d * 128 + h * 16);
  vf4 a0 = __builtin_nontemporal_load(kk + 0);
  vf4 a1 = __builtin_nontemporal_load(kk + 1);
  vf4 a2 = __builtin_nontemporal_load(kk + 2);
  vf4 a3 = __builtin_nontemporal_load(kk + 3);
  vf4 b0 = qq[0], b1 = qq[1], b2 = qq[2], b3 = qq[3];
  float acc = a0.x * b0.x + a0.y * b0.y + a0.z * b0.z + a0.w * b0.w;
  acc += a1.x * b1.x + a1.y * b1.y + a1.z * b1.z + a1.w * b1.w;
  acc += a2.x * b2.x + a2.y * b2.y + a2.z * b2.z + a2.w * b2.w;
  acc += a3.x * b3.x + a3.y * b3.y + a3.z * b3.z + a3.w * b3.w;
  float lg = acc * SCALE;

  int pos = 0;
  if (h == 0) pos = atomicAdd(&cursor[d], 1);
  pos = __shfl(pos, lane & ~7, 64);  // broadcast from the h==0 lane
  if (pos < BSTRIDE) {
    size_t slot = (size_t)d * BSTRIDE + pos;
    if (h == 0) eid[slot] = e;
    lgS[slot * HH + h] = lg;  // 32B contiguous per edge
  }
}

// Pass B: one wave per node: coalesced logit read -> LDS softmax ->
// v-gather accumulate. All LDS wave-private, no __syncthreads.
__global__ __launch_bounds__(256) void node_kernel(
    const float* __restrict__ v, const float* __restrict__ lgS,
    const int* __restrict__ cursor, const int* __restrict__ eid,
    float* __restrict__ out, int N) {
  __shared__ int eidL[4][CAPL];
  __shared__ float wL[4][CAPL * HH];

  int tid = threadIdx.x;
  int wave = tid >> 6;
  int lane = tid & 63;
  int node = blockIdx.x * 4 + wave;
  if (node >= N) return;

  int deg = min(cursor[node], BSTRIDE);
  int nl = min(deg, CAPL);
  const int* bucket = eid + (size_t)node * BSTRIDE;
  const float* lgN = lgS + (size_t)node * (BSTRIDE * HH);
  const char* vB = (const char*)v;
  uint32_t vlane = (uint32_t)(lane * 12);

  for (int i = lane; i < nl; i += 64) eidL[wave][i] = bucket[i];

  // Phase A1: raw logits -> LDS + per-head max. Coalesced: lane i reads
  // lgN[i], h = i&7 == lane&7 (64 % 8 == 0), 256B per iteration.
  float m = -1e30f;
  for (int i = lane; i < nl * 8; i += 64) {
    float lg = lgN[i];
    wL[wave][i] = lg;
    m = fmaxf(m, lg);
  }
  for (int i = CAPL * 8 + lane; i < deg * 8; i += 64)  // overflow (never)
    m = fmaxf(m, lgN[i]);
  m = fmaxf(m, __shfl_xor(m, 8, 64));
  m = fmaxf(m, __shfl_xor(m, 16, 64));
  m = fmaxf(m, __shfl_xor(m, 32, 64));

  // Phase A2: exp in place + denom.
  float s = 0.f;
  for (int i = lane; i < nl * 8; i += 64) {
    float ex = __expf(wL[wave][i] - m);
    wL[wave][i] = ex;
    s += ex;
  }
  for (int i = CAPL * 8 + lane; i < deg * 8; i += 64)  // overflow (never)
    s += __expf(lgN[i] - m);
  s += __shfl_xor(s, 8, 64);
  s += __shfl_xor(s, 16, 64);
  s += __shfl_xor(s, 32, 64);
  float inv = (s > 0.f) ? 1.0f / s : 0.f;  // deg==0 -> zeros, not NaN

  // Phase C: channel accumulation. Lane owns channel `lane`, head hc=lane>>3.
  // Unroll x4: 4 independent dwordx3 v-loads in flight per batch.
  int hc = lane >> 3;
  float minv = __shfl(inv, hc, 64);  // lane hc holds head hc's denom
  float m_c = __shfl(m, hc, 64);
  float a0 = 0.f, a1 = 0.f, a2 = 0.f;
  int i = 0;
  for (; i + 4 <= nl; i += 4) {
    int e0 = eidL[wave][i + 0];
    int e1 = eidL[wave][i + 1];
    int e2 = eidL[wave][i + 2];
    int e3 = eidL[wave][i + 3];
    float w0 = wL[wave][(i + 0) * 8 + hc];
    float w1 = wL[wave][(i + 1) * 8 + hc];
    float w2 = wL[wave][(i + 2) * 8 + hc];
    float w3 = wL[wave][(i + 3) * 8 + hc];
    f3 v0 = *(const f3*)(vB + (uint32_t)e0 * 768u + vlane);
    f3 v1 = *(const f3*)(vB + (uint32_t)e1 * 768u + vlane);
    f3 v2 = *(const f3*)(vB + (uint32_t)e2 * 768u + vlane);
    f3 v3 = *(const f3*)(vB + (uint32_t)e3 * 768u + vlane);
    a0 += w0 * v0.x + w1 * v1.x + w2 * v2.x + w3 * v3.x;
    a1 += w0 * v0.y + w1 * v1.y + w2 * v2.y + w3 * v3.y;
    a2 += w0 * v0.z + w1 * v1.z + w2 * v2.z + w3 * v3.z;
  }
  for (; i < nl; ++i) {
    int e = eidL[wave][i];
    float w = wL[wave][i * 8 + hc];
    f3 vv = *(const f3*)(vB + (uint32_t)e * 768u + vlane);
    a0 += w * vv.x;
    a1 += w * vv.y;
    a2 += w * vv.z;
  }
  for (; i < deg; ++i) {  // overflow (never in practice)
    int e = bucket[i];
    float w = __expf(lgN[i * 8 + hc] - m_c);  // un-normalized, minv at end
    f3 vv = *(const f3*)(vB + (uint32_t)e * 768u + vlane);
    a0 += w * vv.x;
    a1 += w * vv.y;
    a2 += w * vv.z;
  }
  a0 *= minv;
  a1 *= minv;
  a2 *= minv;

  f3* op = (f3*)((char*)out + (uint32_t)node * 768u + vlane);
  op->x = a0;
  op->y = a1;
  op->z = a2;
}

extern "C" void kernel_launch(void* const* d_in, const int* in_sizes, int n_in,
                              void* d_out, int out_size, void* d_ws,
                              size_t ws_size, hipStream_t stream) {
  const float* v = (const float*)d_in[0];
  const float* k = (const float*)d_in[1];
  const float* q = (const float*)d_in[2];
  const int* dst = (const int*)d_in[3];
  float* out = (float*)d_out;

  const int E = in_sizes[3];              // 800000
  const int N = in_sizes[2] / (HH * 16);  // 50000

  // Workspace: cursor[N] | eid[N*256] | lgS[N*256*8]  (~461 MB, ws is ~2.4 GB)
  char* ws = (char*)d_ws;
  size_t off = 0;
  auto take = [&](size_t bytes) {
    void* p = ws + off;
    off += (bytes + 255) & ~(size_t)255;
    return p;
  };
  int* cursor = (int*)take((size_t)N * sizeof(int));
  int* eid = (int*)take((size_t)N * BSTRIDE * sizeof(int));
  float* lgS = (float*)take((size_t)N * BSTRIDE * HH * sizeof(float));

  hipMemsetAsync(cursor, 0, (size_t)N * sizeof(int), stream);
  edge_kernel<<<(E * 8 + 255) / 256, 256, 0, stream>>>(k, q, dst, cursor, eid,
                                                       lgS, E);
  node_kernel<<<(N + 3) / 4, 256, 0, stream>>>(v, lgS, cursor, eid, out, N);
}